// Round 7
// baseline (952.258 us; speedup 1.0000x reference)
//
#include <hip/hip_runtime.h>

#define D_MODEL 1024
#define D_FF    4096
#define N_EXP   8
#define BM 256
#define BN 256
#define BK 64

typedef __attribute__((ext_vector_type(8))) short bf16x8;
typedef __attribute__((ext_vector_type(4))) float f32x4;
typedef unsigned int u32;

__device__ __forceinline__ unsigned short f2bf(float f) {
  union { float f; unsigned u; } v; v.f = f;
  unsigned r = v.u + 0x7FFFu + ((v.u >> 16) & 1u);
  return (unsigned short)(r >> 16);
}

__device__ __forceinline__ void gl_lds16(const void* g, void* l) {
  __builtin_amdgcn_global_load_lds((const __attribute__((address_space(1))) u32*)g,
                                   (__attribute__((address_space(3))) u32*)l, 16, 0, 0);
}

// ---------------- transpose + convert W -> bf16 [e][n][k] ----------------
__global__ __launch_bounds__(256)
void transpose_convert_kernel(const float* __restrict__ src, unsigned short* __restrict__ dst,
                              int Ksub, int Nsrc, int k0, int n0, int Nchunk,
                              unsigned long long eStride) {
  __shared__ u32 s32k[32][65];  // [k/2][n]
  int e = blockIdx.z;
  int kb = blockIdx.x * 64, nb = blockIdx.y * 64;
  const float* se = src + (size_t)e * eStride + (size_t)(k0 + kb) * Nsrc + (n0 + nb);
  unsigned short* de = dst + (size_t)e * Nchunk * Ksub + (size_t)nb * Ksub + kb;
  int tid = threadIdx.x;
  int kh = tid >> 4;
  int n4 = (tid & 15) * 4;
  #pragma unroll
  for (int p = 0; p < 2; p++) {
    int k = kh * 2 + p * 32;
    float4 v0 = *(const float4*)(se + (size_t)k * Nsrc + n4);
    float4 v1 = *(const float4*)(se + (size_t)(k + 1) * Nsrc + n4);
    #pragma unroll
    for (int j = 0; j < 4; j++) {
      u32 pk = (u32)f2bf(((const float*)&v0)[j]) |
               ((u32)f2bf(((const float*)&v1)[j]) << 16);
      s32k[k >> 1][n4 + j] = pk;
    }
  }
  __syncthreads();
  #pragma unroll
  for (int c = 0; c < 2; c++) {
    int id = tid + c * 256;
    int n = id >> 3, kc = id & 7;
    uint4 o;
    o.x = s32k[kc * 4 + 0][n];
    o.y = s32k[kc * 4 + 1][n];
    o.z = s32k[kc * 4 + 2][n];
    o.w = s32k[kc * 4 + 3][n];
    *(uint4*)(de + (size_t)n * Ksub + kc * 8) = o;
  }
}

// ---------------- gating (+ fused x->bf16 convert): 1 wave per token ----------------
__global__ void gating_kernel(const float* __restrict__ x,
                              const float* __restrict__ Wg,
                              const float* __restrict__ bg,
                              float* __restrict__ gate_out,
                              unsigned short* __restrict__ xb,
                              int* __restrict__ cnt,
                              int* __restrict__ tokIdx,
                              float* __restrict__ tokW, int T) {
  int wv = threadIdx.x >> 6, lane = threadIdx.x & 63;
  int t = blockIdx.x * 4 + wv;
  if (t >= T) return;
  const float* xr = x + (size_t)t * D_MODEL + lane * 16;
  float acc[N_EXP];
  #pragma unroll
  for (int e = 0; e < N_EXP; e++) acc[e] = 0.f;
  ushort4 xc[4];
  #pragma unroll
  for (int q = 0; q < 4; q++) {
    float4 xv = *(const float4*)(xr + q * 4);
    xc[q].x = f2bf(xv.x); xc[q].y = f2bf(xv.y);
    xc[q].z = f2bf(xv.z); xc[q].w = f2bf(xv.w);
    #pragma unroll
    for (int r = 0; r < 4; r++) {
      float xs = ((const float*)&xv)[r];
      const float* wrow = Wg + (size_t)(lane * 16 + q * 4 + r) * N_EXP;
      float4 wa = *(const float4*)wrow;
      float4 wb = *(const float4*)(wrow + 4);
      acc[0] += xs * wa.x; acc[1] += xs * wa.y; acc[2] += xs * wa.z; acc[3] += xs * wa.w;
      acc[4] += xs * wb.x; acc[5] += xs * wb.y; acc[6] += xs * wb.z; acc[7] += xs * wb.w;
    }
  }
  unsigned short* xbr = xb + (size_t)t * D_MODEL + lane * 16;
  #pragma unroll
  for (int q = 0; q < 4; q++) *(ushort4*)(xbr + q * 4) = xc[q];
  #pragma unroll
  for (int off = 32; off > 0; off >>= 1) {
    #pragma unroll
    for (int e = 0; e < N_EXP; e++) acc[e] += __shfl_xor(acc[e], off);
  }
  if (lane == 0) {
    float l[N_EXP], p[N_EXP];
    float m = -1e30f;
    #pragma unroll
    for (int e = 0; e < N_EXP; e++) { l[e] = acc[e] + bg[e]; m = fmaxf(m, l[e]); }
    float s = 0.f;
    #pragma unroll
    for (int e = 0; e < N_EXP; e++) { p[e] = __expf(l[e] - m); s += p[e]; }
    float inv = 1.f / s;
    #pragma unroll
    for (int e = 0; e < N_EXP; e++) { p[e] *= inv; gate_out[(size_t)t * N_EXP + e] = p[e]; }
    int e1 = 0;
    #pragma unroll
    for (int e = 1; e < N_EXP; e++) if (p[e] > p[e1]) e1 = e;
    int e2 = (e1 == 0) ? 1 : 0;
    #pragma unroll
    for (int e = 0; e < N_EXP; e++) if (e != e1 && p[e] > p[e2]) e2 = e;
    int pos = atomicAdd(cnt + e1, 1);
    tokIdx[(size_t)e1 * T + pos] = t; tokW[(size_t)e1 * T + pos] = p[e1];
    pos = atomicAdd(cnt + e2, 1);
    tokIdx[(size_t)e2 * T + pos] = t; tokW[(size_t)e2 * T + pos] = p[e2];
  }
}

// ---------------- schedule: build row-tile table ----------------
__global__ void schedule_kernel(const int* __restrict__ cnt, int* __restrict__ meta,
                                int* __restrict__ tE, int* __restrict__ tB,
                                int* __restrict__ tV, int T, int maxTiles) {
  if (threadIdx.x != 0 || blockIdx.x != 0) return;
  int t = 0;
  for (int e = 0; e < N_EXP; e++) {
    int c = cnt[e];
    for (int r = 0; r < c && t < maxTiles; r += BM) {
      tE[t] = e; tB[t] = e * T + r; tV[t] = min(BM, c - r); t++;
    }
  }
  meta[0] = t;
}

// ======== 2-phase dbuf K-loop (T3 minimum recipe, no sched pinning) ========
// Buffer b (ushort idx) at b*32768: A rows [0,16384), B rows [16384,32768).
#define STAGE(bufbase, kt) do { \
    _Pragma("unroll") for (int c_ = 0; c_ < 4; c_++) { \
      gl_lds16(srcA[c_] + (size_t)(kt) * BK, (bufbase) + (w * 32 + c_ * 8) * 64); \
      gl_lds16(srcB[c_] + (size_t)(kt) * BK, (bufbase) + 16384 + (w * 32 + c_ * 8) * 64); } \
  } while (0)

#define RD_A(cur, qm) { _Pragma("unroll") for (int m_ = 0; m_ < 4; m_++) { \
    int row_ = (qm) * 128 + wm64 + m_ * 16 + l15; \
    _Pragma("unroll") for (int kk_ = 0; kk_ < 2; kk_++) \
      a[m_][kk_] = *(const bf16x8*)&(cur)[row_ * 64 + (((kk_ * 4 + l4 + row_) & 7) << 3)]; } }

#define RD_B(cur, qn, bb) { _Pragma("unroll") for (int n_ = 0; n_ < 2; n_++) { \
    int rb_ = (qn) * 128 + wn32 + n_ * 16 + l15; \
    _Pragma("unroll") for (int kk_ = 0; kk_ < 2; kk_++) \
      bb[n_][kk_] = *(const bf16x8*)&(cur)[16384 + rb_ * 64 + (((kk_ * 4 + l4 + rb_) & 7) << 3)]; } }

#define MQ(qm, qn, bb) { _Pragma("unroll") for (int m_ = 0; m_ < 4; m_++) \
    _Pragma("unroll") for (int n_ = 0; n_ < 2; n_++) { \
      acc[qm][qn][m_][n_] = __builtin_amdgcn_mfma_f32_16x16x32_bf16(a[m_][0], bb[n_][0], acc[qm][qn][m_][n_], 0, 0, 0); \
      acc[qm][qn][m_][n_] = __builtin_amdgcn_mfma_f32_16x16x32_bf16(a[m_][1], bb[n_][1], acc[qm][qn][m_][n_], 0, 0, 0); } }

#define KLOOP(NT) \
  STAGE(As, 0); \
  asm volatile("s_waitcnt vmcnt(0)" ::: "memory"); \
  __builtin_amdgcn_s_barrier(); \
  asm volatile("" ::: "memory"); \
  for (int kt = 0; kt < (NT); kt++) { \
    unsigned short* cur = As + (kt & 1) * 32768; \
    unsigned short* nxt = As + ((kt + 1) & 1) * 32768; \
    if (kt + 1 < (NT)) STAGE(nxt, kt + 1); \
    __builtin_amdgcn_s_setprio(1); \
    RD_A(cur, 0); RD_B(cur, 0, rb0); RD_B(cur, 1, rb1); \
    MQ(0, 0, rb0); MQ(0, 1, rb1); \
    RD_A(cur, 1); \
    MQ(1, 1, rb1); MQ(1, 0, rb0); \
    __builtin_amdgcn_s_setprio(0); \
    asm volatile("s_waitcnt vmcnt(0)" ::: "memory"); \
    __builtin_amdgcn_s_barrier(); \
    asm volatile("" ::: "memory"); \
  }

#define ACC_INIT() f32x4 acc[2][2][4][2]; \
  _Pragma("unroll") for (int qm = 0; qm < 2; qm++) \
    _Pragma("unroll") for (int qn = 0; qn < 2; qn++) \
      _Pragma("unroll") for (int m = 0; m < 4; m++) \
        _Pragma("unroll") for (int n = 0; n < 2; n++) acc[qm][qn][m][n] = (f32x4){0.f, 0.f, 0.f, 0.f};

// ---------------- GEMM1: h = relu(x_bf16 @ W1 + b1) ----------------
__global__ __launch_bounds__(512, 1)
void gemm1_kernel(const unsigned short* __restrict__ xb,
                  const unsigned short* __restrict__ w1t,  // [e][FFC][D_MODEL] bf16
                  const float* __restrict__ bias1,
                  const int* __restrict__ meta,
                  const int* __restrict__ tE, const int* __restrict__ tB,
                  const int* __restrict__ tV, const int* __restrict__ tokIdx,
                  unsigned short* __restrict__ hbuf, int FFC, int chunk_off, int ncolLog2) {
  __shared__ unsigned short As[65536];  // 128 KiB, 2 dbuf halves

  int total = gridDim.x;
  int L = blockIdx.x;
  int q = total >> 3, r8 = total & 7;
  int xcd = L & 7, idx = L >> 3;
  int work = (xcd < r8) ? (xcd * (q + 1) + idx) : (r8 * (q + 1) + (xcd - r8) * q + idx);
  int ncol = 1 << ncolLog2;
  int tile = work >> ncolLog2;
  int cb = work & (ncol - 1);
  if (tile >= meta[0]) return;
  int e = tE[tile], base = tB[tile], valid = tV[tile];
  int tid = threadIdx.x;

  int w = tid >> 6, lane = tid & 63;
  int wm = w >> 2, wn = w & 3;
  int wm64 = wm * 64, wn32 = wn * 32;
  int l15 = lane & 15, l4 = lane >> 4;
  int sr = lane >> 3, scg = lane & 7;

  const unsigned short* panel = w1t + (size_t)e * FFC * D_MODEL;
  const unsigned short* srcA[4];
  const unsigned short* srcB[4];
  #pragma unroll
  for (int c = 0; c < 4; c++) {
    int r = w * 32 + c * 8 + sr;
    int rc = r < valid ? r : valid - 1;
    int tok = tokIdx[base + rc];
    int swz = ((scg - r) & 7) << 3;
    srcA[c] = xb + (size_t)tok * D_MODEL + swz;
    srcB[c] = panel + (size_t)(cb * BN + r) * D_MODEL + swz;
  }

  ACC_INIT();
  bf16x8 a[4][2], rb0[2][2], rb1[2][2];
  KLOOP(D_MODEL / BK);

  const float* b1e = bias1 + (size_t)e * D_FF + chunk_off + cb * BN;
  #pragma unroll
  for (int qn = 0; qn < 2; qn++)
    #pragma unroll
    for (int n = 0; n < 2; n++) {
      int colL = qn * 128 + wn32 + n * 16 + l15;
      float bias = b1e[colL];
      #pragma unroll
      for (int qm = 0; qm < 2; qm++)
        #pragma unroll
        for (int m = 0; m < 4; m++)
          #pragma unroll
          for (int r = 0; r < 4; r++) {
            int row = qm * 128 + wm64 + m * 16 + l4 * 4 + r;
            float v = acc[qm][qn][m][n][r] + bias;
            v = v > 0.f ? v : 0.f;
            hbuf[(size_t)(tile * BM + row) * FFC + cb * BN + colL] = f2bf(v);
          }
    }
}

// ---------------- GEMM2: out += w * (h @ W2 + b2)  (K-split 4, scatter) ----------------
__global__ __launch_bounds__(512, 1)
void gemm2_kernel(const unsigned short* __restrict__ hbuf,
                  const unsigned short* __restrict__ w2t,  // [e][D_MODEL][FFC] bf16
                  const float* __restrict__ bias2,
                  const int* __restrict__ meta,
                  const int* __restrict__ tE, const int* __restrict__ tB,
                  const int* __restrict__ tV, const int* __restrict__ tokIdx,
                  const float* __restrict__ tokW,
                  float* __restrict__ out, int FFC, int chunk) {
  __shared__ unsigned short As[65536];
  __shared__ int stok[BM];
  __shared__ float swt[BM];

  int total = gridDim.x;
  int L = blockIdx.x;
  int q = total >> 3, r8 = total & 7;
  int xcd = L & 7, idx = L >> 3;
  int work = (xcd < r8) ? (xcd * (q + 1) + idx) : (r8 * (q + 1) + (xcd - r8) * q + idx);
  int tile = work >> 4;          // 4 col-blocks x 4 k-splits
  int cb = (work >> 2) & 3;
  int ks = work & 3;
  if (tile >= meta[0]) return;
  int e = tE[tile], base = tB[tile], valid = tV[tile];
  int tid = threadIdx.x;

  if (tid < BM) {
    int rr = tid < valid ? tid : valid - 1;
    stok[tid] = tokIdx[base + rr];
    swt[tid] = tokW[base + rr];
  }

  int w = tid >> 6, lane = tid & 63;
  int wm = w >> 2, wn = w & 3;
  int wm64 = wm * 64, wn32 = wn * 32;
  int l15 = lane & 15, l4 = lane >> 4;
  int sr = lane >> 3, scg = lane & 7;

  const int nt = FFC / BK / 4;   // K-tiles per split (16 at FFC=4096)
  const int ksOff = ks * nt * BK;

  const unsigned short* panel = w2t + (size_t)e * D_MODEL * FFC;
  const unsigned short* srcA[4];
  const unsigned short* srcB[4];
  #pragma unroll
  for (int c = 0; c < 4; c++) {
    int r = w * 32 + c * 8 + sr;
    int swz = ((scg - r) & 7) << 3;
    srcA[c] = hbuf + (size_t)(tile * BM + r) * FFC + ksOff + swz;
    srcB[c] = panel + (size_t)(cb * BN + r) * FFC + ksOff + swz;
  }

  ACC_INIT();
  bf16x8 a[4][2], rb0[2][2], rb1[2][2];
  KLOOP(nt);

  int addBias = (chunk == 0 && ks == 0) ? 1 : 0;
  #pragma unroll
  for (int qn = 0; qn < 2; qn++)
    #pragma unroll
    for (int n = 0; n < 2; n++) {
      int colg = cb * BN + qn * 128 + wn32 + n * 16 + l15;
      float bias = addBias ? bias2[(size_t)e * D_MODEL + colg] : 0.f;
      #pragma unroll
      for (int qm = 0; qm < 2; qm++)
        #pragma unroll
        for (int m = 0; m < 4; m++)
          #pragma unroll
          for (int r = 0; r < 4; r++) {
            int row = qm * 128 + wm64 + m * 16 + l4 * 4 + r;
            if (row < valid) {
              float v = (acc[qm][qn][m][n][r] + bias) * swt[row];
              atomicAdd(out + (size_t)stok[row] * D_MODEL + colg, v);
            }
          }
    }
}

// ---------------- host ----------------
extern "C" void kernel_launch(void* const* d_in, const int* in_sizes, int n_in,
                              void* d_out, int out_size, void* d_ws, size_t ws_size,
                              hipStream_t stream) {
  const float* x  = (const float*)d_in[0];
  const float* W1 = (const float*)d_in[1];
  const float* b1 = (const float*)d_in[2];
  const float* W2 = (const float*)d_in[3];
  const float* b2 = (const float*)d_in[4];
  const float* Wg = (const float*)d_in[5];
  const float* bg = (const float*)d_in[6];

  int T = in_sizes[0] / D_MODEL;  // 8192
  float* out = (float*)d_out;
  float* gate_out = out + (size_t)T * D_MODEL;

  char* ws = (char*)d_ws;
  int* cnt  = (int*)(ws + 0);
  int* meta = (int*)(ws + 64);
  int* tE   = (int*)(ws + 128);
  int* tB   = (int*)(ws + 1024);
  int* tV   = (int*)(ws + 2048);
  size_t off = 4096;
  int* tokIdx = (int*)(ws + off);   off += (size_t)N_EXP * T * 4;
  float* tokW = (float*)(ws + off); off += (size_t)N_EXP * T * 4;
  unsigned short* xb = (unsigned short*)(ws + off); off += (size_t)T * D_MODEL * 2;
  off = (off + 255) & ~(size_t)255;

  int maxTiles = (2 * T) / BM + N_EXP;  // 72
  int FFC = D_FF;
  while (FFC > 256 &&
         off + (size_t)FFC * (16384 + 16384 + (size_t)maxTiles * BM * 2) > ws_size)
    FFC >>= 1;

  unsigned short* w1t = (unsigned short*)(ws + off); off += (size_t)FFC * 16384;
  unsigned short* w2t = (unsigned short*)(ws + off); off += (size_t)FFC * 16384;
  unsigned short* h   = (unsigned short*)(ws + off);

  hipMemsetAsync(d_out, 0, (size_t)T * D_MODEL * sizeof(float), stream);
  hipMemsetAsync(cnt, 0, N_EXP * sizeof(int), stream);

  gating_kernel<<<(T + 3) / 4, 256, 0, stream>>>(x, Wg, bg, gate_out, xb, cnt, tokIdx, tokW, T);
  schedule_kernel<<<1, 64, 0, stream>>>(cnt, meta, tE, tB, tV, T, maxTiles);

  int ncol1 = FFC / BN;                 // 16 at FFC=4096
  int ncol1Log2 = __builtin_ctz(ncol1);
  for (int c = 0; c * FFC < D_FF; c++) {
    transpose_convert_kernel<<<dim3(D_MODEL / 64, FFC / 64, N_EXP), 256, 0, stream>>>(
        W1, w1t, D_MODEL, D_FF, 0, c * FFC, FFC, (unsigned long long)D_MODEL * D_FF);
    transpose_convert_kernel<<<dim3(FFC / 64, D_MODEL / 64, N_EXP), 256, 0, stream>>>(
        W2, w2t, FFC, D_MODEL, c * FFC, 0, D_MODEL, (unsigned long long)D_FF * D_MODEL);
    gemm1_kernel<<<maxTiles * ncol1, 512, 0, stream>>>(
        xb, w1t, b1, meta, tE, tB, tV, tokIdx, h, FFC, c * FFC, ncol1Log2);
    gemm2_kernel<<<maxTiles * 4 * 4, 512, 0, stream>>>(
        h, w2t, b2, meta, tE, tB, tV, tokIdx, tokW, out, FFC, c);
  }
}

// Round 8
// 791.883 us; speedup vs baseline: 1.2025x; 1.2025x over previous
//
#include <hip/hip_runtime.h>

#define D_MODEL 1024
#define D_FF    4096
#define N_EXP   8
#define BM 128
#define BN 128
#define BK 64

typedef __attribute__((ext_vector_type(8))) short bf16x8;
typedef __attribute__((ext_vector_type(4))) float f32x4;
typedef unsigned int u32;

__device__ __forceinline__ unsigned short f2bf(float f) {
  union { float f; unsigned u; } v; v.f = f;
  unsigned r = v.u + 0x7FFFu + ((v.u >> 16) & 1u);
  return (unsigned short)(r >> 16);
}

__device__ __forceinline__ void gl_lds16(const void* g, void* l) {
  __builtin_amdgcn_global_load_lds((const __attribute__((address_space(1))) u32*)g,
                                   (__attribute__((address_space(3))) u32*)l, 16, 0, 0);
}

// ---------------- transpose + convert W -> bf16 [e][n][k] ----------------
__global__ __launch_bounds__(256)
void transpose_convert_kernel(const float* __restrict__ src, unsigned short* __restrict__ dst,
                              int Ksub, int Nsrc, int k0, int n0, int Nchunk,
                              unsigned long long eStride) {
  __shared__ u32 s32k[32][65];  // [k/2][n]
  int e = blockIdx.z;
  int kb = blockIdx.x * 64, nb = blockIdx.y * 64;
  const float* se = src + (size_t)e * eStride + (size_t)(k0 + kb) * Nsrc + (n0 + nb);
  unsigned short* de = dst + (size_t)e * Nchunk * Ksub + (size_t)nb * Ksub + kb;
  int tid = threadIdx.x;
  int kh = tid >> 4;
  int n4 = (tid & 15) * 4;
  #pragma unroll
  for (int p = 0; p < 2; p++) {
    int k = kh * 2 + p * 32;
    float4 v0 = *(const float4*)(se + (size_t)k * Nsrc + n4);
    float4 v1 = *(const float4*)(se + (size_t)(k + 1) * Nsrc + n4);
    #pragma unroll
    for (int j = 0; j < 4; j++) {
      u32 pk = (u32)f2bf(((const float*)&v0)[j]) |
               ((u32)f2bf(((const float*)&v1)[j]) << 16);
      s32k[k >> 1][n4 + j] = pk;
    }
  }
  __syncthreads();
  #pragma unroll
  for (int c = 0; c < 2; c++) {
    int id = tid + c * 256;
    int n = id >> 3, kc = id & 7;
    uint4 o;
    o.x = s32k[kc * 4 + 0][n];
    o.y = s32k[kc * 4 + 1][n];
    o.z = s32k[kc * 4 + 2][n];
    o.w = s32k[kc * 4 + 3][n];
    *(uint4*)(de + (size_t)n * Ksub + kc * 8) = o;
  }
}

// ---------------- gating (+ fused x->bf16 convert): 1 wave per token ----------------
__global__ void gating_kernel(const float* __restrict__ x,
                              const float* __restrict__ Wg,
                              const float* __restrict__ bg,
                              float* __restrict__ gate_out,
                              unsigned short* __restrict__ xb,
                              int* __restrict__ cnt,
                              int* __restrict__ tokIdx,
                              float* __restrict__ tokW, int T) {
  int wv = threadIdx.x >> 6, lane = threadIdx.x & 63;
  int t = blockIdx.x * 4 + wv;
  if (t >= T) return;
  const float* xr = x + (size_t)t * D_MODEL + lane * 16;
  float acc[N_EXP];
  #pragma unroll
  for (int e = 0; e < N_EXP; e++) acc[e] = 0.f;
  ushort4 xc[4];
  #pragma unroll
  for (int q = 0; q < 4; q++) {
    float4 xv = *(const float4*)(xr + q * 4);
    xc[q].x = f2bf(xv.x); xc[q].y = f2bf(xv.y);
    xc[q].z = f2bf(xv.z); xc[q].w = f2bf(xv.w);
    #pragma unroll
    for (int r = 0; r < 4; r++) {
      float xs = ((const float*)&xv)[r];
      const float* wrow = Wg + (size_t)(lane * 16 + q * 4 + r) * N_EXP;
      float4 wa = *(const float4*)wrow;
      float4 wb = *(const float4*)(wrow + 4);
      acc[0] += xs * wa.x; acc[1] += xs * wa.y; acc[2] += xs * wa.z; acc[3] += xs * wa.w;
      acc[4] += xs * wb.x; acc[5] += xs * wb.y; acc[6] += xs * wb.z; acc[7] += xs * wb.w;
    }
  }
  unsigned short* xbr = xb + (size_t)t * D_MODEL + lane * 16;
  #pragma unroll
  for (int q = 0; q < 4; q++) *(ushort4*)(xbr + q * 4) = xc[q];
  #pragma unroll
  for (int off = 32; off > 0; off >>= 1) {
    #pragma unroll
    for (int e = 0; e < N_EXP; e++) acc[e] += __shfl_xor(acc[e], off);
  }
  if (lane == 0) {
    float l[N_EXP], p[N_EXP];
    float m = -1e30f;
    #pragma unroll
    for (int e = 0; e < N_EXP; e++) { l[e] = acc[e] + bg[e]; m = fmaxf(m, l[e]); }
    float s = 0.f;
    #pragma unroll
    for (int e = 0; e < N_EXP; e++) { p[e] = __expf(l[e] - m); s += p[e]; }
    float inv = 1.f / s;
    #pragma unroll
    for (int e = 0; e < N_EXP; e++) { p[e] *= inv; gate_out[(size_t)t * N_EXP + e] = p[e]; }
    int e1 = 0;
    #pragma unroll
    for (int e = 1; e < N_EXP; e++) if (p[e] > p[e1]) e1 = e;
    int e2 = (e1 == 0) ? 1 : 0;
    #pragma unroll
    for (int e = 0; e < N_EXP; e++) if (e != e1 && p[e] > p[e2]) e2 = e;
    int pos = atomicAdd(cnt + e1, 1);
    tokIdx[(size_t)e1 * T + pos] = t; tokW[(size_t)e1 * T + pos] = p[e1];
    pos = atomicAdd(cnt + e2, 1);
    tokIdx[(size_t)e2 * T + pos] = t; tokW[(size_t)e2 * T + pos] = p[e2];
  }
}

// ---------------- schedule: build row-tile table ----------------
__global__ void schedule_kernel(const int* __restrict__ cnt, int* __restrict__ meta,
                                int* __restrict__ tE, int* __restrict__ tB,
                                int* __restrict__ tV, int T, int maxTiles) {
  if (threadIdx.x != 0 || blockIdx.x != 0) return;
  int t = 0;
  for (int e = 0; e < N_EXP; e++) {
    int c = cnt[e];
    for (int r = 0; r < c && t < maxTiles; r += BM) {
      tE[t] = e; tB[t] = e * T + r; tV[t] = min(BM, c - r); t++;
    }
  }
  meta[0] = t;
}

// ---------------- GEMM1: h = relu(x_bf16 @ W1 + b1)  (grouped) ----------------
__global__ __launch_bounds__(256)
void gemm1_kernel(const unsigned short* __restrict__ xb,
                  const unsigned short* __restrict__ w1t,  // [e][FFC][D_MODEL] bf16
                  const float* __restrict__ b1,
                  const int* __restrict__ meta,
                  const int* __restrict__ tE, const int* __restrict__ tB,
                  const int* __restrict__ tV, const int* __restrict__ tokIdx,
                  unsigned short* __restrict__ h, int FFC, int chunk_off, int ncolLog2) {
  __shared__ unsigned short As[BM * BK];
  __shared__ unsigned short Bs[BN * BK];
  __shared__ int stok[BM];

  int total = gridDim.x;
  int L = blockIdx.x;
  int q = total >> 3, r8 = total & 7;
  int xcd = L & 7, idx = L >> 3;
  int work = (xcd < r8) ? (xcd * (q + 1) + idx) : (r8 * (q + 1) + (xcd - r8) * q + idx);
  int ncol = 1 << ncolLog2;
  int tile = work >> ncolLog2;
  int cb = work & (ncol - 1);
  if (tile >= meta[0]) return;
  int e = tE[tile], base = tB[tile], valid = tV[tile];
  int tid = threadIdx.x;

  if (tid < BM) stok[tid] = tokIdx[base + (tid < valid ? tid : valid - 1)];
  __syncthreads();

  int w = tid >> 6, lane = tid & 63;
  int lr = lane >> 3, lc = lane & 7;

  const unsigned short* panel = w1t + (size_t)e * FFC * D_MODEL;
  const unsigned short* aBase[4];
  const unsigned short* bBase[4];
  #pragma unroll
  for (int p = 0; p < 4; p++) {
    int row = (w * 4 + p) * 8 + lr;
    int cA = (lc - row) & 7;
    aBase[p] = xb + (size_t)stok[row] * D_MODEL + cA * 8;
    int cB = (lc - row) & 7;
    bBase[p] = panel + (size_t)(cb * BN + row) * D_MODEL + cB * 8;
  }

  int wr = w >> 1, wc = w & 1;
  int l15 = lane & 15, l4 = lane >> 4;
  int aOff[2][4], bOff[2][4];
  #pragma unroll
  for (int kk = 0; kk < 2; kk++) {
    #pragma unroll
    for (int m = 0; m < 4; m++) {
      int row = wr * 64 + m * 16 + l15;
      int c = kk * 4 + l4;
      aOff[kk][m] = row * 64 + (((c + row) & 7) << 3);
      int col = wc * 64 + m * 16 + l15;
      bOff[kk][m] = col * 64 + (((c + col) & 7) << 3);
    }
  }

  f32x4 acc[4][4];
  #pragma unroll
  for (int m = 0; m < 4; m++)
    #pragma unroll
    for (int n = 0; n < 4; n++) acc[m][n] = (f32x4){0.f, 0.f, 0.f, 0.f};

  for (int kt = 0; kt < D_MODEL / BK; kt++) {
    #pragma unroll
    for (int p = 0; p < 4; p++)
      gl_lds16(aBase[p] + kt * BK, &As[(w * 4 + p) * 512]);
    #pragma unroll
    for (int p = 0; p < 4; p++)
      gl_lds16(bBase[p] + kt * BK, &Bs[(w * 4 + p) * 512]);
    __syncthreads();
    #pragma unroll
    for (int kk = 0; kk < 2; kk++) {
      bf16x8 a[4], b[4];
      #pragma unroll
      for (int m = 0; m < 4; m++) a[m] = *(const bf16x8*)&As[aOff[kk][m]];
      #pragma unroll
      for (int n = 0; n < 4; n++) b[n] = *(const bf16x8*)&Bs[bOff[kk][n]];
      #pragma unroll
      for (int m = 0; m < 4; m++)
        #pragma unroll
        for (int n = 0; n < 4; n++)
          acc[m][n] = __builtin_amdgcn_mfma_f32_16x16x32_bf16(a[m], b[n], acc[m][n], 0, 0, 0);
    }
    __syncthreads();
  }

  #pragma unroll
  for (int n = 0; n < 4; n++) {
    int colc = cb * BN + wc * 64 + n * 16 + l15;
    float bias = b1[(size_t)e * D_FF + chunk_off + colc];
    #pragma unroll
    for (int m = 0; m < 4; m++) {
      #pragma unroll
      for (int r = 0; r < 4; r++) {
        int row = wr * 64 + m * 16 + l4 * 4 + r;
        float v = acc[m][n][r] + bias;
        v = v > 0.f ? v : 0.f;
        h[(size_t)(tile * BM + row) * FFC + colc] = f2bf(v);
      }
    }
  }
}

// ---------------- GEMM2: out += w * (h @ W2 + b2)  (grouped, scatter, K-split 2) ----------------
__global__ __launch_bounds__(256)
void gemm2_kernel(const unsigned short* __restrict__ h,
                  const unsigned short* __restrict__ w2t,  // [e][D_MODEL][FFC] bf16
                  const float* __restrict__ b2,
                  const int* __restrict__ meta,
                  const int* __restrict__ tE, const int* __restrict__ tB,
                  const int* __restrict__ tV, const int* __restrict__ tokIdx,
                  const float* __restrict__ tokW,
                  float* __restrict__ out, int FFC, int chunk_off) {
  __shared__ unsigned short As[BM * BK];
  __shared__ unsigned short Bs[BN * BK];
  __shared__ int stok[BM];
  __shared__ float sw[BM];

  int total = gridDim.x;
  int L = blockIdx.x;
  int q = total >> 3, r8 = total & 7;
  int xcd = L & 7, idx = L >> 3;
  int work = (xcd < r8) ? (xcd * (q + 1) + idx) : (r8 * (q + 1) + (xcd - r8) * q + idx);
  int tile = work >> 4;          // 8 col-blocks x 2 k-splits
  int cb = (work >> 1) & 7;
  int ks = work & 1;
  if (tile >= meta[0]) return;
  int e = tE[tile], base = tB[tile], valid = tV[tile];
  int tid = threadIdx.x;

  if (tid < BM) {
    int rr = tid < valid ? tid : valid - 1;
    stok[tid] = tokIdx[base + rr];
    sw[tid] = tokW[base + rr];
  }
  __syncthreads();

  int w = tid >> 6, lane = tid & 63;
  int lr = lane >> 3, lc = lane & 7;

  const int KT = FFC / BK / 2;         // K-tiles per split
  const int ksOff = ks * KT * BK;

  const unsigned short* panel = w2t + (size_t)e * D_MODEL * FFC;
  const unsigned short* aBase[4];
  const unsigned short* bBase[4];
  #pragma unroll
  for (int p = 0; p < 4; p++) {
    int row = (w * 4 + p) * 8 + lr;
    int cA = (lc - row) & 7;
    aBase[p] = h + (size_t)(tile * BM + row) * FFC + ksOff + cA * 8;
    int cB = (lc - row) & 7;
    bBase[p] = panel + (size_t)(cb * BN + row) * FFC + ksOff + cB * 8;
  }

  int wr = w >> 1, wc = w & 1;
  int l15 = lane & 15, l4 = lane >> 4;
  int aOff[2][4], bOff[2][4];
  #pragma unroll
  for (int kk = 0; kk < 2; kk++) {
    #pragma unroll
    for (int m = 0; m < 4; m++) {
      int row = wr * 64 + m * 16 + l15;
      int c = kk * 4 + l4;
      aOff[kk][m] = row * 64 + (((c + row) & 7) << 3);
      int col = wc * 64 + m * 16 + l15;
      bOff[kk][m] = col * 64 + (((c + col) & 7) << 3);
    }
  }

  f32x4 acc[4][4];
  #pragma unroll
  for (int m = 0; m < 4; m++)
    #pragma unroll
    for (int n = 0; n < 4; n++) acc[m][n] = (f32x4){0.f, 0.f, 0.f, 0.f};

  for (int kt = 0; kt < KT; kt++) {
    #pragma unroll
    for (int p = 0; p < 4; p++)
      gl_lds16(aBase[p] + kt * BK, &As[(w * 4 + p) * 512]);
    #pragma unroll
    for (int p = 0; p < 4; p++)
      gl_lds16(bBase[p] + kt * BK, &Bs[(w * 4 + p) * 512]);
    __syncthreads();
    #pragma unroll
    for (int kk = 0; kk < 2; kk++) {
      bf16x8 a[4], b[4];
      #pragma unroll
      for (int m = 0; m < 4; m++) a[m] = *(const bf16x8*)&As[aOff[kk][m]];
      #pragma unroll
      for (int n = 0; n < 4; n++) b[n] = *(const bf16x8*)&Bs[bOff[kk][n]];
      #pragma unroll
      for (int m = 0; m < 4; m++)
        #pragma unroll
        for (int n = 0; n < 4; n++)
          acc[m][n] = __builtin_amdgcn_mfma_f32_16x16x32_bf16(a[m], b[n], acc[m][n], 0, 0, 0);
    }
    __syncthreads();
  }

  int addBias = (chunk_off == 0 && ks == 0) ? 1 : 0;
  #pragma unroll
  for (int n = 0; n < 4; n++) {
    int colg = cb * BN + wc * 64 + n * 16 + l15;
    float bias = addBias ? b2[(size_t)e * D_MODEL + colg] : 0.f;
    #pragma unroll
    for (int m = 0; m < 4; m++) {
      #pragma unroll
      for (int r = 0; r < 4; r++) {
        int row = wr * 64 + m * 16 + l4 * 4 + r;
        if (row < valid) {
          float v = (acc[m][n][r] + bias) * sw[row];
          atomicAdd(out + (size_t)stok[row] * D_MODEL + colg, v);
        }
      }
    }
  }
}

// ---------------- host ----------------
extern "C" void kernel_launch(void* const* d_in, const int* in_sizes, int n_in,
                              void* d_out, int out_size, void* d_ws, size_t ws_size,
                              hipStream_t stream) {
  const float* x  = (const float*)d_in[0];
  const float* W1 = (const float*)d_in[1];
  const float* b1 = (const float*)d_in[2];
  const float* W2 = (const float*)d_in[3];
  const float* b2 = (const float*)d_in[4];
  const float* Wg = (const float*)d_in[5];
  const float* bg = (const float*)d_in[6];

  int T = in_sizes[0] / D_MODEL;  // 8192
  float* out = (float*)d_out;
  float* gate_out = out + (size_t)T * D_MODEL;

  char* ws = (char*)d_ws;
  int* cnt  = (int*)(ws + 0);
  int* meta = (int*)(ws + 64);
  int* tE   = (int*)(ws + 128);
  int* tB   = (int*)(ws + 1024);
  int* tV   = (int*)(ws + 2048);
  size_t off = 4096;
  int* tokIdx = (int*)(ws + off);   off += (size_t)N_EXP * T * 4;
  float* tokW = (float*)(ws + off); off += (size_t)N_EXP * T * 4;
  unsigned short* xb = (unsigned short*)(ws + off); off += (size_t)T * D_MODEL * 2;
  off = (off + 255) & ~(size_t)255;

  int maxTiles = (2 * T) / BM + N_EXP;  // 136
  int FFC = D_FF;
  while (FFC > 256 &&
         off + (size_t)FFC * (16384 + 16384 + (size_t)maxTiles * BM * 2) > ws_size)
    FFC >>= 1;

  unsigned short* w1t = (unsigned short*)(ws + off); off += (size_t)FFC * 16384;
  unsigned short* w2t = (unsigned short*)(ws + off); off += (size_t)FFC * 16384;
  unsigned short* h   = (unsigned short*)(ws + off);

  hipMemsetAsync(d_out, 0, (size_t)T * D_MODEL * sizeof(float), stream);
  hipMemsetAsync(cnt, 0, N_EXP * sizeof(int), stream);

  gating_kernel<<<(T + 3) / 4, 256, 0, stream>>>(x, Wg, bg, gate_out, xb, cnt, tokIdx, tokW, T);
  schedule_kernel<<<1, 64, 0, stream>>>(cnt, meta, tE, tB, tV, T, maxTiles);

  int ncol1 = FFC / BN;
  int ncol1Log2 = __builtin_ctz(ncol1);
  for (int c = 0; c * FFC < D_FF; c++) {
    transpose_convert_kernel<<<dim3(D_MODEL / 64, FFC / 64, N_EXP), 256, 0, stream>>>(
        W1, w1t, D_MODEL, D_FF, 0, c * FFC, FFC, (unsigned long long)D_MODEL * D_FF);
    transpose_convert_kernel<<<dim3(FFC / 64, D_MODEL / 64, N_EXP), 256, 0, stream>>>(
        W2, w2t, FFC, D_MODEL, c * FFC, 0, D_MODEL, (unsigned long long)D_FF * D_MODEL);
    gemm1_kernel<<<maxTiles * ncol1, 256, 0, stream>>>(
        xb, w1t, b1, meta, tE, tB, tV, tokIdx, h, FFC, c * FFC, ncol1Log2);
    gemm2_kernel<<<maxTiles * (D_MODEL / BN) * 2, 256, 0, stream>>>(
        h, w2t, b2, meta, tE, tB, tV, tokIdx, tokW, out, FFC, c * FFC);
  }
}